// Round 13
// baseline (214.755 us; speedup 1.0000x reference)
//
#include <hip/hip_runtime.h>

#define N 32
#define C 256
#define HW 1024
#define S 64
#define LOG2E 1.4426950408889634f

typedef _Float16 f16;
typedef _Float16 f16x4 __attribute__((ext_vector_type(4)));
typedef _Float16 f16x8 __attribute__((ext_vector_type(8)));
typedef float f32x4 __attribute__((ext_vector_type(4)));

#define MFMA(a, b, c) __builtin_amdgcn_mfma_f32_16x16x32_f16(a, b, c, 0, 0, 0)
// Round-10: raw v_exp_f32 (args are post-max-subtraction <= ~0; denorm->0 ok).
// Confirmed r11: -12us on k_fused, VALUBusy 50->32.
#define EXP2(x) __builtin_amdgcn_exp2f(x)

// 16B-aligned LDS f16x8 load -> single ds_read_b128 (rows padded to 16B strides)
__device__ inline f16x8 lds_ld8(const f16* p) {
    return *(const f16x8*)p;
}

// ---------- pool pass 1 (+ weight conversion fold): float4 stream ----------
__global__ void __launch_bounds__(256) k_pool1(const float* seg, const float* edge,
        f16* segf, float* pms, float* pme, float* mean,
        const float* Ws1, const float* Ws11, const float* Wg, f16* Wf, f16* Wgf) {
    int n = blockIdx.x, cg = blockIdx.y;          // grid (32, 32), 8 c per block
    int t = threadIdx.x, w = t >> 6, lane = t & 63;
    int flat = n * 32 + cg;
    if (flat < 256) {                              // weight conversion fold
        int i = flat * 256 + t;
        if (i < S * C) { Wf[i] = (f16)Ws1[i]; Wf[S * C + i] = (f16)Ws11[i]; }
        Wgf[i] = (f16)Wg[i];
    }
    int p4 = (lane << 2) + (w << 8);
    size_t base = (size_t)n * C * HW;
    float4 ms = make_float4(-3e38f, -3e38f, -3e38f, -3e38f);
    float4 me = ms;
    __shared__ float psum[4][8];
    for (int ci = 0; ci < 8; ci++) {
        int c = cg * 8 + ci;
        size_t off = base + (size_t)c * HW + p4;
        float4 s = *(const float4*)(seg + off);
        float4 e = *(const float4*)(edge + off);
        union { f16 h[4]; unsigned long long u; } pk;
        pk.h[0] = (f16)s.x; pk.h[1] = (f16)s.y; pk.h[2] = (f16)s.z; pk.h[3] = (f16)s.w;
        *(unsigned long long*)(segf + off) = pk.u;
        ms.x = fmaxf(ms.x, s.x); ms.y = fmaxf(ms.y, s.y);
        ms.z = fmaxf(ms.z, s.z); ms.w = fmaxf(ms.w, s.w);
        me.x = fmaxf(me.x, s.x * e.x); me.y = fmaxf(me.y, s.y * e.y);
        me.z = fmaxf(me.z, s.z * e.z); me.w = fmaxf(me.w, s.w * e.w);
        float sm = s.x + s.y + s.z + s.w;
        for (int o = 32; o; o >>= 1) sm += __shfl_down(sm, o);
        if (lane == 0) psum[w][ci] = sm;
    }
    __syncthreads();
    if (t < 8)
        mean[n * C + cg * 8 + t] =
            (psum[0][t] + psum[1][t] + psum[2][t] + psum[3][t]) * (1.0f / HW);
    size_t pb = ((size_t)n * 32 + cg) * HW + p4;
    *(float4*)(pms + pb) = ms;
    *(float4*)(pme + pb) = me;
}

// ---------- projections (+ folded k_dp + folded k_pool2 + chat) ----------
// BYTE-IDENTICAL to round-12 (sT XOR-swizzle kept: null but harmless).
__global__ void __launch_bounds__(512) k_proj(const f16* segf, const f16* Wf,
        const float* bs1, const float* bs11, const float* mean,
        const float* Wmlp, const float* bmlp,
        const float* pms, const float* pme,
        const float* ws2, const float* bs2, const float* ws3, const float* bs3,
        f16* segc, float* dp2, float* e_, float* dpmm2, float* a2, float* bq) {
    int n = blockIdx.x, qt = blockIdx.y;   // grid (32, 16)
    int q0 = qt * 64;
    __shared__ f16 sT[64][264];   // [q][c^swz] staging (264: 528B stride)
    __shared__ f16 pT[64][72];    // seg_s tile [row][q_local] (144B stride)
    __shared__ float cA[S];
    __shared__ float cpart[S][4];
    __shared__ float aP[64][4], bP[64][4];
    const f16* sb = segf + (size_t)n * C * HW + q0;
    int tid = threadIdx.x;
    for (int idx = tid; idx < 2048; idx += 512) {
        int c = idx >> 3, q8 = (idx & 7) << 3;
        f16x8 v = *(const f16x8*)(sb + (size_t)c * HW + q8);
        int cs = c ^ ((idx & 7) << 3);         // swz: q>>3 = idx&7 for this q8
        for (int j = 0; j < 8; j++) sT[q8 + j][cs] = v[j];
    }
    if (tid < 256) {               // chat partials: s = tid>>2, quarter = tid&3
        int s = tid >> 2, qp = tid & 3;
        const float* wr = Wmlp + (size_t)s * C + qp * 64;
        const float* mr = mean + (size_t)n * C + qp * 64;
        float acc = 0.f;
        for (int i = 0; i < 64; i++) acc += mr[i] * wr[i];
        cpart[s][qp] = acc;
    } else {                       // pool2 partials: ql x 4 groups x 8 cg
        int idx = tid - 256;
        int ql = idx & 63, g4 = idx >> 6;
        float M = -3e38f, E = -3e38f;
        for (int i = 0; i < 8; i++) {
            int cg = g4 * 8 + i;
            size_t pb = ((size_t)n * 32 + cg) * HW + q0 + ql;
            M = fmaxf(M, pms[pb]);
            E = fmaxf(E, pme[pb]);
        }
        aP[ql][g4] = E; bP[ql][g4] = M;
    }
    __syncthreads();
    if (tid < S) {
        cA[tid] = fmaxf(cpart[tid][0] + cpart[tid][1] + cpart[tid][2]
                        + cpart[tid][3] + bmlp[tid], 0.f);
    } else if (tid >= 448) {       // combine pool2 partials, write a2/bq
        int ql = tid - 448;
        float E = fmaxf(fmaxf(aP[ql][0], aP[ql][1]), fmaxf(aP[ql][2], aP[ql][3]));
        float M = fmaxf(fmaxf(bP[ql][0], bP[ql][1]), fmaxf(bP[ql][2], bP[ql][3]));
        a2[(size_t)n * HW + q0 + ql] = (E * ws3[0] + bs3[0]) * LOG2E;
        bq[(size_t)n * HW + q0 + ql] = M * ws2[0] + bs2[0];
    }
    int lane = tid & 63, wv = tid >> 6;
    int lm = lane & 15, lg = lane >> 4;
    f32x4 acc[4] = {};
    for (int ck = 0; ck < 8; ck++) {
        int c0 = ck * 32;
        f16x8 a0 = *(const f16x8*)(Wf + (size_t)(wv * 16 + lm) * C + c0 + lg * 8);
        for (int j = 0; j < 4; j++) {
            int row = j * 16 + lm;
            int col = (c0 + lg * 8) ^ ((((row >> 3)) & 7) << 3);   // same swz
            f16x8 b = lds_ld8(&sT[row][col]);
            acc[j] = MFMA(a0, b, acc[j]);
        }
    }
    for (int rr = 0; rr < 4; rr++) {
        int row = wv * 16 + lg * 4 + rr;
        float bias = (row < S) ? bs1[row] : bs11[row - S];
        for (int j = 0; j < 4; j++) {
            int q = q0 + j * 16 + lm;
            float v = acc[j][rr] + bias;
            if (row < S) pT[row][j * 16 + lm] = (f16)v;
            else         segc[((size_t)n * S + (row - S)) * HW + q] = (f16)v;
        }
    }
    __syncthreads();
    if (tid < 64) {
        // dp2[p], p = 16*tid + qt : contiguous 64-strip = pT row tid
        float a2c = 0.f;
        for (int t = 0; t < S; t += 8) {
            f16x8 v = lds_ld8(&pT[tid][t]);
            for (int j = 0; j < 8; j++) a2c += (float)v[j] * cA[t + j];
        }
        float d2 = a2c * LOG2E;
        dp2[(size_t)n * HW + 16 * tid + qt] = d2;
        float mx = d2, mn = d2;
        for (int o = 32; o; o >>= 1) {
            mx = fmaxf(mx, __shfl_down(mx, o));
            mn = fminf(mn, __shfl_down(mn, o));
        }
        if (tid == 0) {
            dpmm2[(n * 16 + qt) * 2]     = mx;
            dpmm2[(n * 16 + qt) * 2 + 1] = mn;
        }
    } else if (tid < 128) {
        int ql = tid - 64;     // e[q] = sum_t chat[t] * seg_s[t][q]
        float a2c = 0.f;
        for (int t = 0; t < S; t++) a2c += cA[t] * (float)pT[t][ql];
        e_[(size_t)n * HW + q0 + ql] = a2c;
    }
}

// ---------- fused: STATS + sigma -> weights -> seg_sim -> Wg GEMM -> out ----------
// Round-13: pass-1 softmax goes LANE-LOCAL — the old per-(chk,j) cross-lane
// reduce was 4 dependent shfl_xor (~30cy each) x 32 = ~4-5K serial cycles/wave
// with only 4 waves/SIMD to hide it. Each lane now keeps (m,l) over its own
// 32 p-values; one 2-step shfl_xor merge per j at the end (112 of 128 shfls
// removed, per-chk chain is pure VALU). zc Z-loop: 4-way accumulator unroll
// breaks the 128-deep dependent add chain. Everything else = round-11 body.
// Ledger: r1 -85%; r2 null; r3 null; r4 -13%; r7 zs-fold -14.6; r8 +8.2 (rev);
// r9 null; r11 exp2-direct -12; r12 proj-swz null.
__global__ void __launch_bounds__(512, 4) k_fused(const f16* segf, const f16* segc,
        const float* dp2, const float* e_, const float* a2, const float* bq,
        const float* dpmm2, const f16* Wgf, const float* bg, float* out) {
    int n = blockIdx.x, q0 = blockIdx.y * 64;   // n-major grid (32, 16)
    __shared__ f16 bT[64][72];        // segc^T tile [q][t], 144B stride
    __shared__ f16 wT[2][64][136];    // dbuf weight tile [q][p_local], 272B stride
    __shared__ float2 da[HW];         // (dp2, a2) pairs
    __shared__ float mred[64][9], lred[64][9];   // per-wave sim_s stat partials
    __shared__ float msL[64], izsL[64], mcL[64], izcL[64];
    const f16* cb = segc + (size_t)n * S * HW;
    const f16* sb = segf + (size_t)n * C * HW;
    int tid = threadIdx.x;
    for (int idx = tid; idx < 64 * 32; idx += 512) {
        int q = idx & 63, th = (idx >> 6) << 1;
        union { f16 h[2]; unsigned u; } pk;
        pk.h[0] = cb[(size_t)th * HW + q0 + q];
        pk.h[1] = cb[(size_t)(th + 1) * HW + q0 + q];
        *(unsigned*)&bT[q][th] = pk.u;
    }
    for (int i = tid; i < HW; i += 512)
        da[i] = make_float2(dp2[(size_t)n * HW + i], a2[(size_t)n * HW + i]);
    __syncthreads();
    int w = tid >> 6, lane = tid & 63, lm = lane & 15, lg = lane >> 4;
    float ev[4], bqv[4];
    for (int j = 0; j < 4; j++) {
        size_t gq = (size_t)n * HW + q0 + j * 16 + lm;
        ev[j] = e_[gq];  bqv[j] = bq[gq];
    }
    // ---- pass 1: sim_s online stats, lane-local (no per-chk cross-lane) ----
    float sm[4], sl[4];
    #pragma unroll
    for (int j = 0; j < 4; j++) { sm[j] = -3e38f; sl[j] = 0.f; }
    for (int chk = 0; chk < 8; chk++) {
        int p0 = chk * 128;
        const f16* sp = cb + (size_t)(p0 + w * 16 + lm) * S;
        f16x8 sa0 = *(const f16x8*)(sp + lg * 8);
        f16x8 sa1 = *(const f16x8*)(sp + 32 + lg * 8);
        float avr[4];
        #pragma unroll
        for (int rr = 0; rr < 4; rr++) avr[rr] = da[p0 + w * 16 + lg * 4 + rr].y;
        #pragma unroll
        for (int j = 0; j < 4; j++) {
            f16x8 bb0 = lds_ld8(&bT[j * 16 + lm][lg * 8]);
            f16x8 bb1 = lds_ld8(&bT[j * 16 + lm][32 + lg * 8]);
            f32x4 sg = {};
            sg = MFMA(sa0, bb0, sg);
            sg = MFMA(sa1, bb1, sg);
            float sc[4], fm = -3e38f;
            #pragma unroll
            for (int rr = 0; rr < 4; rr++) {
                sc[rr] = avr[rr] * bqv[j] * sg[rr];
                fm = fmaxf(fm, sc[rr]);
            }
            float nm = fmaxf(sm[j], fm);
            float fl = 0.f;
            #pragma unroll
            for (int rr = 0; rr < 4; rr++) fl += EXP2(sc[rr] - nm);
            sl[j] = sl[j] * EXP2(sm[j] - nm) + fl;
            sm[j] = nm;
        }
    }
    // one cross-lane (m,l) merge per j across lg (lanes sharing lm)
    #pragma unroll
    for (int j = 0; j < 4; j++) {
        #pragma unroll
        for (int o = 16; o <= 32; o <<= 1) {
            float om = __shfl_xor(sm[j], o);
            float ol = __shfl_xor(sl[j], o);
            float nm = fmaxf(sm[j], om);
            sl[j] = sl[j] * EXP2(sm[j] - nm) + ol * EXP2(om - nm);
            sm[j] = nm;
        }
    }
    if (lg == 0)
        #pragma unroll
        for (int j = 0; j < 4; j++) {
            mred[j * 16 + lm][w] = sm[j];
            lred[j * 16 + lm][w] = sl[j];
        }
    // ---- sim_c Z (old k_zc): 8 thr/q over staged da, 4-way acc unroll ----
    {
        float mx = -3e38f, mn = 3e38f;
        for (int j2 = 0; j2 < 16; j2++) {
            mx = fmaxf(mx, dpmm2[(n * 16 + j2) * 2]);
            mn = fminf(mn, dpmm2[(n * 16 + j2) * 2 + 1]);
        }
        int qz = tid >> 3, pi = tid & 7;
        float eqz = e_[(size_t)n * HW + q0 + qz];
        float mzv = (eqz > 0.f) ? eqz * mx : eqz * mn;
        float z0 = 0.f, z1 = 0.f, z2 = 0.f, z3 = 0.f;
        for (int j2 = 0; j2 < 128; j2 += 4) {
            z0 += EXP2(da[pi + 8 * j2].x * eqz - mzv);
            z1 += EXP2(da[pi + 8 * (j2 + 1)].x * eqz - mzv);
            z2 += EXP2(da[pi + 8 * (j2 + 2)].x * eqz - mzv);
            z3 += EXP2(da[pi + 8 * (j2 + 3)].x * eqz - mzv);
        }
        float z = (z0 + z1) + (z2 + z3);
        z += __shfl_xor(z, 1);
        z += __shfl_xor(z, 2);
        z += __shfl_xor(z, 4);
        if (pi == 0) { mcL[qz] = mzv; izcL[qz] = 1.f / z; }
    }
    __syncthreads();
    if (tid < 64) {        // combine 8 wave-partials -> Ms, 1/Ls
        float M = mred[tid][0];
        for (int ww = 1; ww < 8; ww++) M = fmaxf(M, mred[tid][ww]);
        float L = 0.f;
        for (int ww = 0; ww < 8; ww++) L += lred[tid][ww] * EXP2(mred[tid][ww] - M);
        msL[tid] = M; izsL[tid] = 1.f / L;
    }
    __syncthreads();
    float mcv[4], izcv[4], msv[4], izsv[4];
    #pragma unroll
    for (int j = 0; j < 4; j++) {
        int q = j * 16 + lm;
        mcv[j] = mcL[q]; izcv[j] = izcL[q];
        msv[j] = msL[q]; izsv[j] = izsL[q];
    }
    // ---- pass 2: round-3 body (consume-before-produce, dbuf wT) ----
    f32x4 acc[2][4] = {};   // 32 c-rows (w*32) x 64 q
    for (int chk = 0; chk <= 8; chk++) {
        if (chk > 0) {      // consume first: global loads issue at interval start
            int p0 = (chk - 1) * 128;
            int cur = (chk - 1) & 1;
            #pragma unroll
            for (int ks = 0; ks < 4; ks++) {
                f16x8 a2f[2];
                #pragma unroll
                for (int cf = 0; cf < 2; cf++) {
                    int crow = w * 32 + cf * 16 + lm;
                    a2f[cf] = *(const f16x8*)(sb + (size_t)crow * HW + p0 + ks * 32 + lg * 8);
                }
                #pragma unroll
                for (int qf = 0; qf < 4; qf++) {
                    f16x8 bb = lds_ld8(&wT[cur][qf * 16 + lm][ks * 32 + lg * 8]);
                    acc[0][qf] = MFMA(a2f[0], bb, acc[0][qf]);
                    acc[1][qf] = MFMA(a2f[1], bb, acc[1][qf]);
                }
            }
        }
        if (chk < 8) {
            int p0 = chk * 128;
            const f16* sp = cb + (size_t)(p0 + w * 16 + lm) * S;
            f16x8 sa0 = *(const f16x8*)(sp + lg * 8);
            f16x8 sa1 = *(const f16x8*)(sp + 32 + lg * 8);
            float d2r[4], avr[4];
            #pragma unroll
            for (int rr = 0; rr < 4; rr++) {
                float2 dv = da[p0 + w * 16 + lg * 4 + rr];
                d2r[rr] = dv.x; avr[rr] = dv.y;
            }
            #pragma unroll
            for (int j = 0; j < 4; j++) {
                f16x8 bb0 = lds_ld8(&bT[j * 16 + lm][lg * 8]);
                f16x8 bb1 = lds_ld8(&bT[j * 16 + lm][32 + lg * 8]);
                f32x4 sg = {};
                sg = MFMA(sa0, bb0, sg);
                sg = MFMA(sa1, bb1, sg);
                float wgt[4];
                #pragma unroll
                for (int rr = 0; rr < 4; rr++) {
                    float wc  = EXP2(d2r[rr] * ev[j] - mcv[j]) * izcv[j];
                    float wsv = EXP2(avr[rr] * bqv[j] * sg[rr] - msv[j]) * izsv[j];
                    wgt[rr] = wc + wsv;
                }
                int ql = j * 16 + lm;
                int pp = w * 16 + lg * 4;
                union { f16 h[2]; unsigned u; } c0u, c1u;
                c0u.h[0] = (f16)wgt[0]; c0u.h[1] = (f16)wgt[1];
                c1u.h[0] = (f16)wgt[2]; c1u.h[1] = (f16)wgt[3];
                *(unsigned*)&wT[chk & 1][ql][pp]     = c0u.u;
                *(unsigned*)&wT[chk & 1][ql][pp + 2] = c1u.u;
            }
        }
        __syncthreads();
    }
    // ---- folded k_out epilogue: seg_sim tile -> LDS (overlay dead wT) ----
    f16 (*sT2)[264] = (f16(*)[264])&wT[0][0][0];   // 64*264*2 = 33792 <= 34816 B
    for (int cf = 0; cf < 2; cf++)
        for (int qf = 0; qf < 4; qf++) {
            int crow = w * 32 + cf * 16 + lg * 4;
            int ql = qf * 16 + lm;
            f16x4 pk;
            pk[0] = (f16)acc[cf][qf][0]; pk[1] = (f16)acc[cf][qf][1];
            pk[2] = (f16)acc[cf][qf][2]; pk[3] = (f16)acc[cf][qf][3];
            *(f16x4*)&sT2[ql][crow] = pk;
        }
    __syncthreads();
    int ow = w * 32;
    f32x4 acc2[2][4] = {};
    for (int ck = 0; ck < 8; ck++) {
        int c0 = ck * 32;
        f16x8 af0 = *(const f16x8*)(Wgf + (size_t)(ow + lm) * C + c0 + lg * 8);
        f16x8 af1 = *(const f16x8*)(Wgf + (size_t)(ow + 16 + lm) * C + c0 + lg * 8);
        for (int qf = 0; qf < 4; qf++) {
            f16x8 bf = lds_ld8(&sT2[qf * 16 + lm][c0 + lg * 8]);
            acc2[0][qf] = MFMA(af0, bf, acc2[0][qf]);
            acc2[1][qf] = MFMA(af1, bf, acc2[1][qf]);
        }
    }
    for (int of = 0; of < 2; of++)
        for (int rr = 0; rr < 4; rr++) {
            int o = ow + of * 16 + lg * 4 + rr;
            float bgv = bg[o];
            for (int qf = 0; qf < 4; qf++) {
                int q = q0 + qf * 16 + lm;
                size_t ix = ((size_t)n * C + o) * HW + q;
                out[ix] = fmaxf(acc2[of][qf][rr] + bgv, 0.f) + 2.f * (float)sb[((size_t)o * HW) + q];
            }
        }
}

extern "C" void kernel_launch(void* const* d_in, const int* in_sizes, int n_in,
                              void* d_out, int out_size, void* d_ws, size_t ws_size,
                              hipStream_t stream) {
    const float* seg  = (const float*)d_in[0];
    const float* edge = (const float*)d_in[1];
    const float* Ws1  = (const float*)d_in[2];
    const float* bs1  = (const float*)d_in[3];
    const float* Ws11 = (const float*)d_in[4];
    const float* bs11 = (const float*)d_in[5];
    const float* Wmlp = (const float*)d_in[6];
    const float* bmlp = (const float*)d_in[7];
    const float* ws2  = (const float*)d_in[8];
    const float* bs2  = (const float*)d_in[9];
    const float* ws3  = (const float*)d_in[10];
    const float* bs3  = (const float*)d_in[11];
    const float* Wg   = (const float*)d_in[12];
    const float* bg   = (const float*)d_in[13];
    float* out = (float*)d_out;
    char* wsb = (char*)d_ws;

    f16*   segf   = (f16*)(wsb);                   // 16777216 B
    f16*   segc   = (f16*)(wsb + 16777216);        //  4194304 B
    float* dpmm2  = (float*)(wsb + 20971520);      //  4096 B
    float* pms    = (float*)(wsb + 25165824);      // 4 MB
    float* pme    = (float*)(wsb + 29360128);      // 4 MB
    f16*   Wf     = (f16*)(wsb + 41943040);        //    65536 B
    f16*   Wgf    = (f16*)(wsb + 42008576);        //   131072 B
    float* mean   = (float*)(wsb + 42139648);      //    32768 B
    float* dp2    = (float*)(wsb + 42180608);      //   131072 B
    float* e_     = (float*)(wsb + 42311680);
    float* a2     = (float*)(wsb + 42442752);
    float* bq     = (float*)(wsb + 42573824);

    k_pool1<<<dim3(32, 32), 256, 0, stream>>>(seg, edge, segf, pms, pme, mean,
                                              Ws1, Ws11, Wg, Wf, Wgf);
    k_proj<<<dim3(32, 16), 512, 0, stream>>>(segf, Wf, bs1, bs11, mean,
                                             Wmlp, bmlp, pms, pme,
                                             ws2, bs2, ws3, bs3,
                                             segc, dp2, e_, dpmm2, a2, bq);
    k_fused<<<dim3(32, 16), 512, 0, stream>>>(segf, segc, dp2, e_, a2, bq,
                                              dpmm2, Wgf, bg, out);
}

// Round 14
// 213.017 us; speedup vs baseline: 1.0082x; 1.0082x over previous
//
#include <hip/hip_runtime.h>

#define N 32
#define C 256
#define HW 1024
#define S 64
#define LOG2E 1.4426950408889634f

typedef _Float16 f16;
typedef _Float16 f16x4 __attribute__((ext_vector_type(4)));
typedef _Float16 f16x8 __attribute__((ext_vector_type(8)));
typedef float f32x4 __attribute__((ext_vector_type(4)));

#define MFMA(a, b, c) __builtin_amdgcn_mfma_f32_16x16x32_f16(a, b, c, 0, 0, 0)
// raw v_exp_f32 (args post-max-subtraction; denorm->0 ok). r11: -12us, VALU 50->32.
#define EXP2(x) __builtin_amdgcn_exp2f(x)

// 16B-aligned LDS f16x8 load -> single ds_read_b128
__device__ inline f16x8 lds_ld8(const f16* p) {
    return *(const f16x8*)p;
}

// ---------- SLIM pool pass: mean + weight conversion ONLY ----------
// Round-14: pool1's only cross-block product was mean; a2/bq maxes are per-hw
// and move into k_proj (whose blocks own all 256 c for their hw strip).
// Drops: edge read (33.5MB), segf write (16.8MB), pms/pme write (16.8MB).
__global__ void __launch_bounds__(256) k_pool1(const float* seg, float* mean,
        const float* Ws1, const float* Ws11, const float* Wg, f16* Wf, f16* Wgf) {
    int n = blockIdx.x, cg = blockIdx.y;          // grid (32, 32), 8 c per block
    int t = threadIdx.x, w = t >> 6, lane = t & 63;
    int flat = n * 32 + cg;
    if (flat < 256) {                              // weight conversion fold
        int i = flat * 256 + t;
        if (i < S * C) { Wf[i] = (f16)Ws1[i]; Wf[S * C + i] = (f16)Ws11[i]; }
        Wgf[i] = (f16)Wg[i];
    }
    int p4 = (lane << 2) + (w << 8);
    size_t base = (size_t)n * C * HW;
    __shared__ float psum[4][8];
    for (int ci = 0; ci < 8; ci++) {
        int c = cg * 8 + ci;
        float4 s = *(const float4*)(seg + base + (size_t)c * HW + p4);
        float sm = s.x + s.y + s.z + s.w;
        for (int o = 32; o; o >>= 1) sm += __shfl_down(sm, o);
        if (lane == 0) psum[w][ci] = sm;
    }
    __syncthreads();
    if (t < 8)
        mean[n * C + cg * 8 + t] =
            (psum[0][t] + psum[1][t] + psum[2][t] + psum[3][t]) * (1.0f / HW);
}

// ---------- FAT projections: seg/edge f32 direct + segf + a2/bq + all of old proj ----------
// Round-14: staging reads seg/edge f32 for (n, all c, q-strip) directly (same
// bytes previously read via segf), converts inline: segf global write, sT fill
// (same XOR swizzle both sides), a2/bq block-local max over c (2 shfl_xor +
// 8-wave LDS combine). pms/pme eliminated. chat/dp2/e_/segc/MFMA unchanged.
__global__ void __launch_bounds__(512) k_proj(const float* seg, const float* edge,
        f16* segf, const f16* Wf,
        const float* bs1, const float* bs11, const float* mean,
        const float* Wmlp, const float* bmlp,
        const float* ws2, const float* bs2, const float* ws3, const float* bs3,
        f16* segc, float* dp2, float* e_, float* dpmm2, float* a2, float* bq) {
    int n = blockIdx.x, qt = blockIdx.y;   // grid (32, 16)
    int q0 = qt * 64;
    __shared__ f16 sT[64][264];   // [q][c^swz] staging (264: 528B stride)
    __shared__ f16 pT[64][72];    // seg_s tile [row][q_local] (144B stride)
    __shared__ float cA[S];
    __shared__ float cpart[S][4];
    __shared__ float psS[8][64], psE[8][64];   // per-wave max partials [wave][hw]
    const float* sgp = seg  + (size_t)n * C * HW + q0;
    const float* egp = edge + (size_t)n * C * HW + q0;
    f16*         sfp = segf + (size_t)n * C * HW + q0;
    int tid = threadIdx.x;
    int f4 = tid & 15;
    {
        float4 ms = make_float4(-3e38f, -3e38f, -3e38f, -3e38f);
        float4 me = ms;
        #pragma unroll
        for (int k = 0; k < 8; k++) {
            int c = (tid >> 4) + 32 * k;
            size_t off = (size_t)c * HW + (f4 << 2);
            float4 s = *(const float4*)(sgp + off);
            float4 e = *(const float4*)(egp + off);
            union { f16 h[4]; unsigned long long u; } pk;
            pk.h[0] = (f16)s.x; pk.h[1] = (f16)s.y;
            pk.h[2] = (f16)s.z; pk.h[3] = (f16)s.w;
            *(unsigned long long*)(sfp + off) = pk.u;
            int cs = c ^ (((f4 >> 1) & 7) << 3);   // row>>3 == f4>>1 for these 4 rows
            sT[f4 * 4 + 0][cs] = pk.h[0];
            sT[f4 * 4 + 1][cs] = pk.h[1];
            sT[f4 * 4 + 2][cs] = pk.h[2];
            sT[f4 * 4 + 3][cs] = pk.h[3];
            ms.x = fmaxf(ms.x, s.x); ms.y = fmaxf(ms.y, s.y);
            ms.z = fmaxf(ms.z, s.z); ms.w = fmaxf(ms.w, s.w);
            me.x = fmaxf(me.x, s.x * e.x); me.y = fmaxf(me.y, s.y * e.y);
            me.z = fmaxf(me.z, s.z * e.z); me.w = fmaxf(me.w, s.w * e.w);
        }
        // reduce across the 4 lanes sharing f4 within this wave (lane ^16, ^32)
        #pragma unroll
        for (int o = 16; o <= 32; o <<= 1) {
            ms.x = fmaxf(ms.x, __shfl_xor(ms.x, o));
            ms.y = fmaxf(ms.y, __shfl_xor(ms.y, o));
            ms.z = fmaxf(ms.z, __shfl_xor(ms.z, o));
            ms.w = fmaxf(ms.w, __shfl_xor(ms.w, o));
            me.x = fmaxf(me.x, __shfl_xor(me.x, o));
            me.y = fmaxf(me.y, __shfl_xor(me.y, o));
            me.z = fmaxf(me.z, __shfl_xor(me.z, o));
            me.w = fmaxf(me.w, __shfl_xor(me.w, o));
        }
        int wv0 = tid >> 6, lane0 = tid & 63;
        if (lane0 < 16) {      // lane0 == f4 here
            psS[wv0][f4 * 4 + 0] = ms.x; psS[wv0][f4 * 4 + 1] = ms.y;
            psS[wv0][f4 * 4 + 2] = ms.z; psS[wv0][f4 * 4 + 3] = ms.w;
            psE[wv0][f4 * 4 + 0] = me.x; psE[wv0][f4 * 4 + 1] = me.y;
            psE[wv0][f4 * 4 + 2] = me.z; psE[wv0][f4 * 4 + 3] = me.w;
        }
    }
    if (tid < 256) {               // chat partials: s = tid>>2, quarter = tid&3
        int s = tid >> 2, qp = tid & 3;
        const float* wr = Wmlp + (size_t)s * C + qp * 64;
        const float* mr = mean + (size_t)n * C + qp * 64;
        float acc = 0.f;
        for (int i = 0; i < 64; i++) acc += mr[i] * wr[i];
        cpart[s][qp] = acc;
    }
    __syncthreads();
    if (tid < S) {
        cA[tid] = fmaxf(cpart[tid][0] + cpart[tid][1] + cpart[tid][2]
                        + cpart[tid][3] + bmlp[tid], 0.f);
    } else if (tid >= 448) {       // combine 8 wave-partials, write a2/bq
        int q = tid - 448;
        float M = -3e38f, E = -3e38f;
        for (int ww = 0; ww < 8; ww++) {
            M = fmaxf(M, psS[ww][q]);
            E = fmaxf(E, psE[ww][q]);
        }
        a2[(size_t)n * HW + q0 + q] = (E * ws3[0] + bs3[0]) * LOG2E;
        bq[(size_t)n * HW + q0 + q] = M * ws2[0] + bs2[0];
    }
    int lane = tid & 63, wv = tid >> 6;
    int lm = lane & 15, lg = lane >> 4;
    f32x4 acc[4] = {};
    for (int ck = 0; ck < 8; ck++) {
        int c0 = ck * 32;
        f16x8 a0 = *(const f16x8*)(Wf + (size_t)(wv * 16 + lm) * C + c0 + lg * 8);
        for (int j = 0; j < 4; j++) {
            int row = j * 16 + lm;
            int col = (c0 + lg * 8) ^ ((((row >> 3)) & 7) << 3);   // same swz
            f16x8 b = lds_ld8(&sT[row][col]);
            acc[j] = MFMA(a0, b, acc[j]);
        }
    }
    for (int rr = 0; rr < 4; rr++) {
        int row = wv * 16 + lg * 4 + rr;
        float bias = (row < S) ? bs1[row] : bs11[row - S];
        for (int j = 0; j < 4; j++) {
            int q = q0 + j * 16 + lm;
            float v = acc[j][rr] + bias;
            if (row < S) pT[row][j * 16 + lm] = (f16)v;
            else         segc[((size_t)n * S + (row - S)) * HW + q] = (f16)v;
        }
    }
    __syncthreads();
    if (tid < 64) {
        // dp2[p], p = 16*tid + qt : contiguous 64-strip = pT row tid
        float a2c = 0.f;
        for (int t = 0; t < S; t += 8) {
            f16x8 v = lds_ld8(&pT[tid][t]);
            for (int j = 0; j < 8; j++) a2c += (float)v[j] * cA[t + j];
        }
        float d2 = a2c * LOG2E;
        dp2[(size_t)n * HW + 16 * tid + qt] = d2;
        float mx = d2, mn = d2;
        for (int o = 32; o; o >>= 1) {
            mx = fmaxf(mx, __shfl_down(mx, o));
            mn = fminf(mn, __shfl_down(mn, o));
        }
        if (tid == 0) {
            dpmm2[(n * 16 + qt) * 2]     = mx;
            dpmm2[(n * 16 + qt) * 2 + 1] = mn;
        }
    } else if (tid < 128) {
        int ql = tid - 64;     // e[q] = sum_t chat[t] * seg_s[t][q]
        float a2c = 0.f;
        for (int t = 0; t < S; t++) a2c += cA[t] * (float)pT[t][ql];
        e_[(size_t)n * HW + q0 + ql] = a2c;
    }
}

// ---------- fused: STATS + sigma -> weights -> seg_sim -> Wg GEMM -> out ----------
// BYTE-IDENTICAL to round-13 (lane-local pass-1 softmax; zc 4-way unroll;
// exp2-direct; pass 2 = round-3 body). Ledger: r1 -85%; r2 null; r3 null;
// r4 -13%; r7 zs-fold -14.6; r8 +8.2 (rev); r9 null; r11 exp2 -12;
// r12 proj-swz null; r13 lane-local-sm null.
__global__ void __launch_bounds__(512, 4) k_fused(const f16* segf, const f16* segc,
        const float* dp2, const float* e_, const float* a2, const float* bq,
        const float* dpmm2, const f16* Wgf, const float* bg, float* out) {
    int n = blockIdx.x, q0 = blockIdx.y * 64;   // n-major grid (32, 16)
    __shared__ f16 bT[64][72];        // segc^T tile [q][t], 144B stride
    __shared__ f16 wT[2][64][136];    // dbuf weight tile [q][p_local], 272B stride
    __shared__ float2 da[HW];         // (dp2, a2) pairs
    __shared__ float mred[64][9], lred[64][9];   // per-wave sim_s stat partials
    __shared__ float msL[64], izsL[64], mcL[64], izcL[64];
    const f16* cb = segc + (size_t)n * S * HW;
    const f16* sb = segf + (size_t)n * C * HW;
    int tid = threadIdx.x;
    for (int idx = tid; idx < 64 * 32; idx += 512) {
        int q = idx & 63, th = (idx >> 6) << 1;
        union { f16 h[2]; unsigned u; } pk;
        pk.h[0] = cb[(size_t)th * HW + q0 + q];
        pk.h[1] = cb[(size_t)(th + 1) * HW + q0 + q];
        *(unsigned*)&bT[q][th] = pk.u;
    }
    for (int i = tid; i < HW; i += 512)
        da[i] = make_float2(dp2[(size_t)n * HW + i], a2[(size_t)n * HW + i]);
    __syncthreads();
    int w = tid >> 6, lane = tid & 63, lm = lane & 15, lg = lane >> 4;
    float ev[4], bqv[4];
    for (int j = 0; j < 4; j++) {
        size_t gq = (size_t)n * HW + q0 + j * 16 + lm;
        ev[j] = e_[gq];  bqv[j] = bq[gq];
    }
    // ---- pass 1: sim_s online stats, lane-local (no per-chk cross-lane) ----
    float sm[4], sl[4];
    #pragma unroll
    for (int j = 0; j < 4; j++) { sm[j] = -3e38f; sl[j] = 0.f; }
    for (int chk = 0; chk < 8; chk++) {
        int p0 = chk * 128;
        const f16* sp = cb + (size_t)(p0 + w * 16 + lm) * S;
        f16x8 sa0 = *(const f16x8*)(sp + lg * 8);
        f16x8 sa1 = *(const f16x8*)(sp + 32 + lg * 8);
        float avr[4];
        #pragma unroll
        for (int rr = 0; rr < 4; rr++) avr[rr] = da[p0 + w * 16 + lg * 4 + rr].y;
        #pragma unroll
        for (int j = 0; j < 4; j++) {
            f16x8 bb0 = lds_ld8(&bT[j * 16 + lm][lg * 8]);
            f16x8 bb1 = lds_ld8(&bT[j * 16 + lm][32 + lg * 8]);
            f32x4 sg = {};
            sg = MFMA(sa0, bb0, sg);
            sg = MFMA(sa1, bb1, sg);
            float sc[4], fm = -3e38f;
            #pragma unroll
            for (int rr = 0; rr < 4; rr++) {
                sc[rr] = avr[rr] * bqv[j] * sg[rr];
                fm = fmaxf(fm, sc[rr]);
            }
            float nm = fmaxf(sm[j], fm);
            float fl = 0.f;
            #pragma unroll
            for (int rr = 0; rr < 4; rr++) fl += EXP2(sc[rr] - nm);
            sl[j] = sl[j] * EXP2(sm[j] - nm) + fl;
            sm[j] = nm;
        }
    }
    // one cross-lane (m,l) merge per j across lg (lanes sharing lm)
    #pragma unroll
    for (int j = 0; j < 4; j++) {
        #pragma unroll
        for (int o = 16; o <= 32; o <<= 1) {
            float om = __shfl_xor(sm[j], o);
            float ol = __shfl_xor(sl[j], o);
            float nm = fmaxf(sm[j], om);
            sl[j] = sl[j] * EXP2(sm[j] - nm) + ol * EXP2(om - nm);
            sm[j] = nm;
        }
    }
    if (lg == 0)
        #pragma unroll
        for (int j = 0; j < 4; j++) {
            mred[j * 16 + lm][w] = sm[j];
            lred[j * 16 + lm][w] = sl[j];
        }
    // ---- sim_c Z (old k_zc): 8 thr/q over staged da, 4-way acc unroll ----
    {
        float mx = -3e38f, mn = 3e38f;
        for (int j2 = 0; j2 < 16; j2++) {
            mx = fmaxf(mx, dpmm2[(n * 16 + j2) * 2]);
            mn = fminf(mn, dpmm2[(n * 16 + j2) * 2 + 1]);
        }
        int qz = tid >> 3, pi = tid & 7;
        float eqz = e_[(size_t)n * HW + q0 + qz];
        float mzv = (eqz > 0.f) ? eqz * mx : eqz * mn;
        float z0 = 0.f, z1 = 0.f, z2 = 0.f, z3 = 0.f;
        for (int j2 = 0; j2 < 128; j2 += 4) {
            z0 += EXP2(da[pi + 8 * j2].x * eqz - mzv);
            z1 += EXP2(da[pi + 8 * (j2 + 1)].x * eqz - mzv);
            z2 += EXP2(da[pi + 8 * (j2 + 2)].x * eqz - mzv);
            z3 += EXP2(da[pi + 8 * (j2 + 3)].x * eqz - mzv);
        }
        float z = (z0 + z1) + (z2 + z3);
        z += __shfl_xor(z, 1);
        z += __shfl_xor(z, 2);
        z += __shfl_xor(z, 4);
        if (pi == 0) { mcL[qz] = mzv; izcL[qz] = 1.f / z; }
    }
    __syncthreads();
    if (tid < 64) {        // combine 8 wave-partials -> Ms, 1/Ls
        float M = mred[tid][0];
        for (int ww = 1; ww < 8; ww++) M = fmaxf(M, mred[tid][ww]);
        float L = 0.f;
        for (int ww = 0; ww < 8; ww++) L += lred[tid][ww] * EXP2(mred[tid][ww] - M);
        msL[tid] = M; izsL[tid] = 1.f / L;
    }
    __syncthreads();
    float mcv[4], izcv[4], msv[4], izsv[4];
    #pragma unroll
    for (int j = 0; j < 4; j++) {
        int q = j * 16 + lm;
        mcv[j] = mcL[q]; izcv[j] = izcL[q];
        msv[j] = msL[q]; izsv[j] = izsL[q];
    }
    // ---- pass 2: round-3 body (consume-before-produce, dbuf wT) ----
    f32x4 acc[2][4] = {};   // 32 c-rows (w*32) x 64 q
    for (int chk = 0; chk <= 8; chk++) {
        if (chk > 0) {      // consume first: global loads issue at interval start
            int p0 = (chk - 1) * 128;
            int cur = (chk - 1) & 1;
            #pragma unroll
            for (int ks = 0; ks < 4; ks++) {
                f16x8 a2f[2];
                #pragma unroll
                for (int cf = 0; cf < 2; cf++) {
                    int crow = w * 32 + cf * 16 + lm;
                    a2f[cf] = *(const f16x8*)(sb + (size_t)crow * HW + p0 + ks * 32 + lg * 8);
                }
                #pragma unroll
                for (int qf = 0; qf < 4; qf++) {
                    f16x8 bb = lds_ld8(&wT[cur][qf * 16 + lm][ks * 32 + lg * 8]);
                    acc[0][qf] = MFMA(a2f[0], bb, acc[0][qf]);
                    acc[1][qf] = MFMA(a2f[1], bb, acc[1][qf]);
                }
            }
        }
        if (chk < 8) {
            int p0 = chk * 128;
            const f16* sp = cb + (size_t)(p0 + w * 16 + lm) * S;
            f16x8 sa0 = *(const f16x8*)(sp + lg * 8);
            f16x8 sa1 = *(const f16x8*)(sp + 32 + lg * 8);
            float d2r[4], avr[4];
            #pragma unroll
            for (int rr = 0; rr < 4; rr++) {
                float2 dv = da[p0 + w * 16 + lg * 4 + rr];
                d2r[rr] = dv.x; avr[rr] = dv.y;
            }
            #pragma unroll
            for (int j = 0; j < 4; j++) {
                f16x8 bb0 = lds_ld8(&bT[j * 16 + lm][lg * 8]);
                f16x8 bb1 = lds_ld8(&bT[j * 16 + lm][32 + lg * 8]);
                f32x4 sg = {};
                sg = MFMA(sa0, bb0, sg);
                sg = MFMA(sa1, bb1, sg);
                float wgt[4];
                #pragma unroll
                for (int rr = 0; rr < 4; rr++) {
                    float wc  = EXP2(d2r[rr] * ev[j] - mcv[j]) * izcv[j];
                    float wsv = EXP2(avr[rr] * bqv[j] * sg[rr] - msv[j]) * izsv[j];
                    wgt[rr] = wc + wsv;
                }
                int ql = j * 16 + lm;
                int pp = w * 16 + lg * 4;
                union { f16 h[2]; unsigned u; } c0u, c1u;
                c0u.h[0] = (f16)wgt[0]; c0u.h[1] = (f16)wgt[1];
                c1u.h[0] = (f16)wgt[2]; c1u.h[1] = (f16)wgt[3];
                *(unsigned*)&wT[chk & 1][ql][pp]     = c0u.u;
                *(unsigned*)&wT[chk & 1][ql][pp + 2] = c1u.u;
            }
        }
        __syncthreads();
    }
    // ---- folded k_out epilogue: seg_sim tile -> LDS (overlay dead wT) ----
    f16 (*sT2)[264] = (f16(*)[264])&wT[0][0][0];   // 64*264*2 = 33792 <= 34816 B
    for (int cf = 0; cf < 2; cf++)
        for (int qf = 0; qf < 4; qf++) {
            int crow = w * 32 + cf * 16 + lg * 4;
            int ql = qf * 16 + lm;
            f16x4 pk;
            pk[0] = (f16)acc[cf][qf][0]; pk[1] = (f16)acc[cf][qf][1];
            pk[2] = (f16)acc[cf][qf][2]; pk[3] = (f16)acc[cf][qf][3];
            *(f16x4*)&sT2[ql][crow] = pk;
        }
    __syncthreads();
    int ow = w * 32;
    f32x4 acc2[2][4] = {};
    for (int ck = 0; ck < 8; ck++) {
        int c0 = ck * 32;
        f16x8 af0 = *(const f16x8*)(Wgf + (size_t)(ow + lm) * C + c0 + lg * 8);
        f16x8 af1 = *(const f16x8*)(Wgf + (size_t)(ow + 16 + lm) * C + c0 + lg * 8);
        for (int qf = 0; qf < 4; qf++) {
            f16x8 bf = lds_ld8(&sT2[qf * 16 + lm][c0 + lg * 8]);
            acc2[0][qf] = MFMA(af0, bf, acc2[0][qf]);
            acc2[1][qf] = MFMA(af1, bf, acc2[1][qf]);
        }
    }
    for (int of = 0; of < 2; of++)
        for (int rr = 0; rr < 4; rr++) {
            int o = ow + of * 16 + lg * 4 + rr;
            float bgv = bg[o];
            for (int qf = 0; qf < 4; qf++) {
                int q = q0 + qf * 16 + lm;
                size_t ix = ((size_t)n * C + o) * HW + q;
                out[ix] = fmaxf(acc2[of][qf][rr] + bgv, 0.f) + 2.f * (float)sb[((size_t)o * HW) + q];
            }
        }
}

extern "C" void kernel_launch(void* const* d_in, const int* in_sizes, int n_in,
                              void* d_out, int out_size, void* d_ws, size_t ws_size,
                              hipStream_t stream) {
    const float* seg  = (const float*)d_in[0];
    const float* edge = (const float*)d_in[1];
    const float* Ws1  = (const float*)d_in[2];
    const float* bs1  = (const float*)d_in[3];
    const float* Ws11 = (const float*)d_in[4];
    const float* bs11 = (const float*)d_in[5];
    const float* Wmlp = (const float*)d_in[6];
    const float* bmlp = (const float*)d_in[7];
    const float* ws2  = (const float*)d_in[8];
    const float* bs2  = (const float*)d_in[9];
    const float* ws3  = (const float*)d_in[10];
    const float* bs3  = (const float*)d_in[11];
    const float* Wg   = (const float*)d_in[12];
    const float* bg   = (const float*)d_in[13];
    float* out = (float*)d_out;
    char* wsb = (char*)d_ws;

    f16*   segf   = (f16*)(wsb);                   // 16777216 B
    f16*   segc   = (f16*)(wsb + 16777216);        //  4194304 B
    float* dpmm2  = (float*)(wsb + 20971520);      //  4096 B
    f16*   Wf     = (f16*)(wsb + 41943040);        //    65536 B
    f16*   Wgf    = (f16*)(wsb + 42008576);        //   131072 B
    float* mean   = (float*)(wsb + 42139648);      //    32768 B
    float* dp2    = (float*)(wsb + 42180608);      //   131072 B
    float* e_     = (float*)(wsb + 42311680);
    float* a2     = (float*)(wsb + 42442752);
    float* bq     = (float*)(wsb + 42573824);

    k_pool1<<<dim3(32, 32), 256, 0, stream>>>(seg, mean, Ws1, Ws11, Wg, Wf, Wgf);
    k_proj<<<dim3(32, 16), 512, 0, stream>>>(seg, edge, segf, Wf, bs1, bs11,
                                             mean, Wmlp, bmlp,
                                             ws2, bs2, ws3, bs3,
                                             segc, dp2, e_, dpmm2, a2, bq);
    k_fused<<<dim3(32, 16), 512, 0, stream>>>(segf, segc, dp2, e_, a2, bq,
                                              dpmm2, Wgf, bg, out);
}